// Round 7
// baseline (1667.408 us; speedup 1.0000x reference)
//
#include <hip/hip_runtime.h>
#include <stdint.h>
#include <stddef.h>

#define BB 8
#define TENC 200
#define UU 100
#define UP1 101
#define VP1 1025
#define ED 128
#define PD 512
#define LSTM_NWG 64

typedef __attribute__((ext_vector_type(8))) unsigned short ushort8;
typedef __attribute__((ext_vector_type(8))) __bf16 bf16x8;
typedef __attribute__((ext_vector_type(4))) float f32x4;

__device__ __forceinline__ float bf2f(unsigned short u){
  unsigned int x = ((unsigned int)u) << 16;
  return __builtin_bit_cast(float, x);
}
__device__ __forceinline__ unsigned short f2bf(float f){
  unsigned int x = __builtin_bit_cast(unsigned int, f);
  unsigned int r = (x + 0x7fffu + ((x >> 16) & 1u)) >> 16;
  return (unsigned short)r;
}
__device__ __forceinline__ float tanh_fast(float x){
  float e = __expf(2.0f * x);
  return 1.0f - 2.0f / (e + 1.0f);
}
__device__ __forceinline__ float sigm(float x){
  return 1.0f / (1.0f + __expf(-x));
}

// ---------------- fp32 -> bf16 convert (W_joint) ----------------
__global__ __launch_bounds__(256) void k_cvt_bf16(const float* __restrict__ src,
                                                  unsigned short* __restrict__ dst, int n){
  int i = blockIdx.x * 256 + threadIdx.x;
  if (i < n) dst[i] = f2bf(src[i]);
}

// ---------------- K1: embedding + x-part of LSTM gates ----------------
__global__ __launch_bounds__(256) void k_xgate(
    const float* __restrict__ emb, const int* __restrict__ targets,
    const float* __restrict__ W_ih, const float* __restrict__ b_ih,
    const float* __restrict__ b_hh, float* __restrict__ xg)
{
  __shared__ float e_s[BB * ED];
  const int u  = blockIdx.x >> 2;
  const int jq = blockIdx.x & 3;
  const int tid = threadIdx.x;
  for (int idx = tid; idx < BB * ED; idx += 256){
    int b = idx >> 7, e = idx & 127;
    int tok = (u == 0) ? 1024 : targets[b * UU + (u - 1)];
    e_s[idx] = emb[(size_t)tok * ED + e];
  }
  __syncthreads();
  float acc[2][BB];
  #pragma unroll
  for (int r = 0; r < 2; r++)
    #pragma unroll
    for (int b = 0; b < BB; b++) acc[r][b] = 0.0f;
  const int j0 = jq * 512 + tid;
  const float* w0p = W_ih + (size_t)j0 * ED;
  const float* w1p = W_ih + (size_t)(j0 + 256) * ED;
  for (int e = 0; e < ED; e++){
    float w0 = w0p[e], w1 = w1p[e];
    #pragma unroll
    for (int b = 0; b < BB; b++){
      float ev = e_s[b * ED + e];
      acc[0][b] = fmaf(ev, w0, acc[0][b]);
      acc[1][b] = fmaf(ev, w1, acc[1][b]);
    }
  }
  #pragma unroll
  for (int r = 0; r < 2; r++){
    int j = j0 + r * 256;
    float bias = b_ih[j] + b_hh[j];
    #pragma unroll
    for (int b = 0; b < BB; b++)
      xg[((size_t)b * UP1 + u) * 2048 + j] = acc[r][b] + bias;
  }
}

// ---------------- K2: persistent LSTM: r3 sync + no-reduce dot ----------------
__global__ __launch_bounds__(256) void k_lstm_all(
    const float* __restrict__ xg, const float* __restrict__ W_hh,
    float* __restrict__ pred, float* __restrict__ hb, unsigned int* __restrict__ cnt)
{
  __shared__ float W_s[32][520];   // 66.5 KB
  __shared__ float h_s[8][520];    // 16.6 KB
  __shared__ float gates_s[32][8];
  const int tid = threadIdx.x;
  const int wg  = blockIdx.x;
  const int p0  = wg * 8;
  const int row = tid >> 3, bb = tid & 7;
  {
    int r = tid >> 3;
    int grow = (r >> 3) * PD + p0 + (r & 7);
    const float* src = W_hh + (size_t)grow * PD;
    for (int c = (tid & 7); c < 128; c += 8)
      *(float4*)&W_s[r][c * 4] = *(const float4*)(src + c * 4);
  }
  float c_reg = 0.0f;   // cell state (tid<64)
  __syncthreads();
  for (int u = 0; u < UP1; u++){
    float xv = xg[((size_t)(bb * UP1 + u)) * 2048 + (row >> 3) * 512 + p0 + (row & 7)];
    if (u > 0){
      if (tid == 0){
        while (__hip_atomic_load(&cnt[u - 1], __ATOMIC_RELAXED, __HIP_MEMORY_SCOPE_AGENT) < LSTM_NWG)
          __builtin_amdgcn_s_sleep(1);
      }
      __syncthreads();
      const float* hsrc = hb + ((u - 1) & 1) * 4096;
      float tmp[16];
      #pragma unroll
      for (int j = 0; j < 16; j++)
        tmp[j] = __hip_atomic_load(hsrc + tid + 256 * j,
                                   __ATOMIC_RELAXED, __HIP_MEMORY_SCOPE_AGENT);
      #pragma unroll
      for (int j = 0; j < 16; j++){
        int i = tid + 256 * j;
        h_s[i >> 9][i & 511] = tmp[j];
      }
    } else {
      for (int i = tid; i < 8 * PD; i += 256) h_s[i >> 9][i & 511] = 0.0f;
    }
    __syncthreads();
    float a0 = 0.f, a1 = 0.f, a2 = 0.f, a3 = 0.f;
    #pragma unroll 4
    for (int k = 0; k < PD; k += 16){
      float4 w0 = *(const float4*)&W_s[row][k],      h0 = *(const float4*)&h_s[bb][k];
      float4 w1 = *(const float4*)&W_s[row][k + 4],  h1 = *(const float4*)&h_s[bb][k + 4];
      float4 w2 = *(const float4*)&W_s[row][k + 8],  h2 = *(const float4*)&h_s[bb][k + 8];
      float4 w3 = *(const float4*)&W_s[row][k + 12], h3 = *(const float4*)&h_s[bb][k + 12];
      a0 = fmaf(w0.x, h0.x, a0); a0 = fmaf(w0.y, h0.y, a0);
      a0 = fmaf(w0.z, h0.z, a0); a0 = fmaf(w0.w, h0.w, a0);
      a1 = fmaf(w1.x, h1.x, a1); a1 = fmaf(w1.y, h1.y, a1);
      a1 = fmaf(w1.z, h1.z, a1); a1 = fmaf(w1.w, h1.w, a1);
      a2 = fmaf(w2.x, h2.x, a2); a2 = fmaf(w2.y, h2.y, a2);
      a2 = fmaf(w2.z, h2.z, a2); a2 = fmaf(w2.w, h2.w, a2);
      a3 = fmaf(w3.x, h3.x, a3); a3 = fmaf(w3.y, h3.y, a3);
      a3 = fmaf(w3.z, h3.z, a3); a3 = fmaf(w3.w, h3.w, a3);
    }
    gates_s[row][bb] = a0 + a1 + a2 + a3 + xv;
    __syncthreads();
    if (tid < 64){
      int pl = tid >> 3, b2 = tid & 7;
      float gi = gates_s[pl][b2];
      float gf = gates_s[8  + pl][b2];
      float gg = gates_s[16 + pl][b2];
      float go = gates_s[24 + pl][b2];
      float iv = sigm(gi), fv = sigm(gf), ov = sigm(go);
      c_reg = fv * c_reg + iv * tanh_fast(gg);
      float hval = ov * tanh_fast(c_reg);
      __hip_atomic_store(hb + (u & 1) * 4096 + b2 * 512 + p0 + pl, hval,
                         __ATOMIC_RELAXED, __HIP_MEMORY_SCOPE_AGENT);
      pred[((size_t)(b2 * UP1 + u)) * PD + p0 + pl] = hval;
    }
    if (u < UP1 - 1 && tid == 0){
      asm volatile("s_waitcnt vmcnt(0)" ::: "memory");
      __hip_atomic_fetch_add(&cnt[u], 1u, __ATOMIC_RELAXED, __HIP_MEMORY_SCOPE_AGENT);
    }
  }
}

// ---------------- K3: fp32 GEMM (A @ W^T + bias) -> bf16 out ----------------
__global__ __launch_bounds__(256) void k_gemm_bias_bf16(
    const float* __restrict__ A, const float* __restrict__ W,
    const float* __restrict__ bias, unsigned short* __restrict__ out, int M)
{
  __shared__ float a_s[16][68];
  __shared__ float b_s[16][68];
  const int m0 = blockIdx.x * 64, n0 = blockIdx.y * 64;
  const int tid = threadIdx.x;
  const int tx = tid & 15, ty = tid >> 4;
  float acc[4][4];
  #pragma unroll
  for (int i2 = 0; i2 < 4; i2++)
    #pragma unroll
    for (int j2 = 0; j2 < 4; j2++) acc[i2][j2] = 0.0f;
  for (int k0 = 0; k0 < 512; k0 += 16){
    int mm = tid >> 2, k4 = (tid & 3) * 4;
    int row = m0 + mm; if (row >= M) row = M - 1;
    float4 av = *(const float4*)(A + (size_t)row * 512 + k0 + k4);
    a_s[k4 + 0][mm] = av.x; a_s[k4 + 1][mm] = av.y;
    a_s[k4 + 2][mm] = av.z; a_s[k4 + 3][mm] = av.w;
    float4 bv = *(const float4*)(W + (size_t)(n0 + mm) * 512 + k0 + k4);
    b_s[k4 + 0][mm] = bv.x; b_s[k4 + 1][mm] = bv.y;
    b_s[k4 + 2][mm] = bv.z; b_s[k4 + 3][mm] = bv.w;
    __syncthreads();
    #pragma unroll
    for (int k = 0; k < 16; k++){
      float4 a4 = *(const float4*)&a_s[k][ty * 4];
      float4 b4 = *(const float4*)&b_s[k][tx * 4];
      float aa[4] = {a4.x, a4.y, a4.z, a4.w};
      float bb[4] = {b4.x, b4.y, b4.z, b4.w};
      #pragma unroll
      for (int i2 = 0; i2 < 4; i2++)
        #pragma unroll
        for (int j2 = 0; j2 < 4; j2++)
          acc[i2][j2] = fmaf(aa[i2], bb[j2], acc[i2][j2]);
    }
    __syncthreads();
  }
  #pragma unroll
  for (int i2 = 0; i2 < 4; i2++){
    int m = m0 + ty * 4 + i2;
    if (m < M){
      #pragma unroll
      for (int j2 = 0; j2 < 4; j2++){
        int n = n0 + tx * 4 + j2;
        out[(size_t)m * 512 + n] = f2bf(acc[i2][j2] + bias[n]);
      }
    }
  }
}

// ---------------- K4: fused joint, A-in-LDS, B from L2 to regs, NO barriers ----------------
// grid (169, 8). Phase 1: A_s[128][512] = tanh(fe+fp) bf16, swizzled, built once.
// Phase 2: wave w: rows [wr*32,+32), cols [wc*512,+512) swept in 8 chunks of 64 cols.
// B fragments loaded straight from global (L2-resident, 1MB), depth-1 reg prefetch.
__global__ __launch_bounds__(512, 1) void k_joint5(
    const unsigned short* __restrict__ fe, const unsigned short* __restrict__ fp,
    const unsigned short* __restrict__ wj, const float* __restrict__ bj,
    float* __restrict__ out)
{
  __shared__ unsigned short A_s[128 * 512];     // 128 KB, swizzled
  const int tu = blockIdx.x;
  const int b  = blockIdx.y;
  const int tt = tu / 13, ut = tu - tt * 13;
  const int t0 = tt * 16, u0 = ut * 8;
  const int tid = threadIdx.x;
  const int w = tid >> 6, l = tid & 63;
  const int l15 = l & 15, lg = l >> 4;
  const int wr = w >> 1, wc = w & 1;

  // ---- phase 1: A_s = tanh(fe + fp) bf16, swizzled, built ONCE ----
  for (int rr = 0; rr < 16; rr++){
    int row = rr * 8 + w;
    int ti = row >> 3, ui = row & 7;
    int t = t0 + ti, uu = u0 + ui;
    ushort8 a = {0,0,0,0,0,0,0,0};
    if (t < TENC && uu < UP1){
      ushort8 f8 = *(const ushort8*)(fe + (size_t)(b * TENC + t) * 512 + l * 8);
      ushort8 p8 = *(const ushort8*)(fp + (size_t)(b * UP1 + uu) * 512 + l * 8);
      #pragma unroll
      for (int j = 0; j < 8; j++)
        a[j] = f2bf(tanh_fast(bf2f(f8[j]) + bf2f(p8[j])));
    }
    int byteo = row * 1024 + ((l * 16) ^ ((row & 7) << 4));
    *(ushort8*)((char*)A_s + byteo) = a;
  }
  __syncthreads();

  // ---- phase 2: per-wave independent GEMM sweep, 8 chunks of 64 cols ----
  for (int c = 0; c < 8; c++){
    const int ncol0 = wc * 512 + c * 64;
    const unsigned short* bbase = wj + (size_t)(ncol0 + l15) * 512 + lg * 8;
    f32x4 acc[2][4];
    #pragma unroll
    for (int fr = 0; fr < 2; fr++)
      #pragma unroll
      for (int fc = 0; fc < 4; fc++)
        acc[fr][fc] = (f32x4){0.f, 0.f, 0.f, 0.f};

    bf16x8 bfr[2][4];
    #pragma unroll
    for (int fc = 0; fc < 4; fc++)
      bfr[0][fc] = *(const bf16x8*)(bbase + (size_t)fc * 16 * 512);

    #pragma unroll
    for (int ks = 0; ks < 16; ks++){
      if (ks < 15){
        #pragma unroll
        for (int fc = 0; fc < 4; fc++)
          bfr[(ks + 1) & 1][fc] = *(const bf16x8*)(bbase + (size_t)fc * 16 * 512 + (ks + 1) * 32);
      }
      bf16x8 afr[2];
      #pragma unroll
      for (int fr = 0; fr < 2; fr++){
        int ra = wr * 32 + fr * 16 + l15;
        int k8 = ks * 4 + lg;
        int byteo = ra * 1024 + ((k8 * 16) ^ ((ra & 7) << 4));
        afr[fr] = __builtin_bit_cast(bf16x8, *(const ushort8*)((const char*)A_s + byteo));
      }
      #pragma unroll
      for (int fr = 0; fr < 2; fr++)
        #pragma unroll
        for (int fc = 0; fc < 4; fc++)
          acc[fr][fc] = __builtin_amdgcn_mfma_f32_16x16x32_bf16(bfr[ks & 1][fc], afr[fr], acc[fr][fc], 0, 0, 0);
    }

    // epilogue: C reg-dim = n, lane l15 = m -> contiguous nontemporal f32x4 stores
    #pragma unroll
    for (int fr = 0; fr < 2; fr++){
      int m = wr * 32 + fr * 16 + l15;
      int t = t0 + (m >> 3), uu2 = u0 + (m & 7);
      if (t < TENC && uu2 < UP1){
        float* orow = out + ((size_t)(b * TENC + t) * UP1 + uu2) * VP1;
        #pragma unroll
        for (int fc = 0; fc < 4; fc++){
          int nb = ncol0 + fc * 16 + lg * 4;
          float4 bv = *(const float4*)(bj + nb);
          f32x4 v = acc[fr][fc];
          f32x4 st = {v[0] + bv.x, v[1] + bv.y, v[2] + bv.z, v[3] + bv.w};
          __builtin_nontemporal_store(st, (f32x4*)(orow + nb));
        }
      }
    }
  }

  // ---- tail: column 1024 (blank logit) ----
  {
    int row = tid >> 2, q = tid & 3;
    float s = 0.0f;
    const unsigned short* w1 = wj + (size_t)1024 * 512;
    #pragma unroll 4
    for (int j = 0; j < 16; j++){
      int k8 = q * 16 + j;
      int byteo = row * 1024 + ((k8 * 16) ^ ((row & 7) << 4));
      ushort8 a8 = *(const ushort8*)((const char*)A_s + byteo);
      ushort8 w8 = *(const ushort8*)(w1 + k8 * 8);
      #pragma unroll
      for (int jj = 0; jj < 8; jj++)
        s += bf2f(a8[jj]) * bf2f(w8[jj]);
    }
    s += __shfl_xor(s, 1);
    s += __shfl_xor(s, 2);
    if (q == 0){
      int t = t0 + (row >> 3), uu = u0 + (row & 7);
      if (t < TENC && uu < UP1)
        out[((size_t)(b * TENC + t) * UP1 + uu) * VP1 + 1024] = s + bj[1024];
    }
  }
}

extern "C" void kernel_launch(void* const* d_in, const int* in_sizes, int n_in,
                              void* d_out, int out_size, void* d_ws, size_t ws_size,
                              hipStream_t stream) {
  const float* enc_out = (const float*)d_in[0];
  const int*   targets = (const int*)d_in[1];
  const float* emb     = (const float*)d_in[3];
  const float* W_ih    = (const float*)d_in[4];
  const float* W_hh    = (const float*)d_in[5];
  const float* b_ih    = (const float*)d_in[6];
  const float* b_hh    = (const float*)d_in[7];
  const float* W_enc   = (const float*)d_in[8];
  const float* b_enc   = (const float*)d_in[9];
  const float* W_pred  = (const float*)d_in[10];
  const float* b_pred  = (const float*)d_in[11];
  const float* W_joint = (const float*)d_in[12];
  const float* b_joint = (const float*)d_in[13];
  float* out = (float*)d_out;

  char* ws = (char*)d_ws;
  float* xg            = (float*)(ws + 0);                  // 6,619,136 B
  float* pred          = (float*)(ws + 6619136);            // 1,654,784 B
  unsigned short* feb  = (unsigned short*)(ws + 8273920);   // 1,638,400 B
  unsigned short* fpb  = (unsigned short*)(ws + 9912320);   //   827,392 B
  unsigned short* wjb  = (unsigned short*)(ws + 10739712);  // 1,049,600 B
  float* hb            = (float*)(ws + 11789312);           //    32,768 B
  unsigned int* cnt    = (unsigned int*)(ws + 11822080);    //       404 B

  (void)hipMemsetAsync(cnt, 0, UP1 * sizeof(unsigned int), stream);
  hipLaunchKernelGGL(k_cvt_bf16, dim3((VP1 * 512 + 255) / 256), dim3(256), 0, stream,
                     W_joint, wjb, VP1 * 512);
  hipLaunchKernelGGL(k_xgate, dim3(404), dim3(256), 0, stream,
                     emb, targets, W_ih, b_ih, b_hh, xg);
  hipLaunchKernelGGL(k_gemm_bias_bf16, dim3(25, 8), dim3(256), 0, stream,
                     enc_out, W_enc, b_enc, feb, 1600);
  hipLaunchKernelGGL(k_lstm_all, dim3(LSTM_NWG), dim3(256), 0, stream,
                     xg, W_hh, pred, hb, cnt);
  hipLaunchKernelGGL(k_gemm_bias_bf16, dim3(13, 8), dim3(256), 0, stream,
                     pred, W_pred, b_pred, fpb, 808);
  hipLaunchKernelGGL(k_joint5, dim3(169, 8), dim3(512), 0, stream,
                     feb, fpb, wjb, b_joint, out);
}

// Round 8
// 1121.738 us; speedup vs baseline: 1.4865x; 1.4865x over previous
//
#include <hip/hip_runtime.h>
#include <stdint.h>
#include <stddef.h>

#define BB 8
#define TENC 200
#define UU 100
#define UP1 101
#define VP1 1025
#define ED 128
#define PD 512
#define LSTM_NWG 64
#define MTOT 161600   // 8*200*101 flattened output rows

typedef __attribute__((ext_vector_type(8))) unsigned short ushort8;
typedef __attribute__((ext_vector_type(8))) __bf16 bf16x8;
typedef __attribute__((ext_vector_type(4))) float f32x4;

__device__ __forceinline__ float bf2f(unsigned short u){
  unsigned int x = ((unsigned int)u) << 16;
  return __builtin_bit_cast(float, x);
}
__device__ __forceinline__ unsigned short f2bf(float f){
  unsigned int x = __builtin_bit_cast(unsigned int, f);
  unsigned int r = (x + 0x7fffu + ((x >> 16) & 1u)) >> 16;
  return (unsigned short)r;
}
__device__ __forceinline__ float tanh_fast(float x){
  float e = __expf(2.0f * x);
  return 1.0f - 2.0f / (e + 1.0f);
}
__device__ __forceinline__ float sigm(float x){
  return 1.0f / (1.0f + __expf(-x));
}

// ---------------- fp32 -> bf16 convert (W_joint) ----------------
__global__ __launch_bounds__(256) void k_cvt_bf16(const float* __restrict__ src,
                                                  unsigned short* __restrict__ dst, int n){
  int i = blockIdx.x * 256 + threadIdx.x;
  if (i < n) dst[i] = f2bf(src[i]);
}

// ---------------- K1: embedding + x-part of LSTM gates ----------------
__global__ __launch_bounds__(256) void k_xgate(
    const float* __restrict__ emb, const int* __restrict__ targets,
    const float* __restrict__ W_ih, const float* __restrict__ b_ih,
    const float* __restrict__ b_hh, float* __restrict__ xg)
{
  __shared__ float e_s[BB * ED];
  const int u  = blockIdx.x >> 2;
  const int jq = blockIdx.x & 3;
  const int tid = threadIdx.x;
  for (int idx = tid; idx < BB * ED; idx += 256){
    int b = idx >> 7, e = idx & 127;
    int tok = (u == 0) ? 1024 : targets[b * UU + (u - 1)];
    e_s[idx] = emb[(size_t)tok * ED + e];
  }
  __syncthreads();
  float acc[2][BB];
  #pragma unroll
  for (int r = 0; r < 2; r++)
    #pragma unroll
    for (int b = 0; b < BB; b++) acc[r][b] = 0.0f;
  const int j0 = jq * 512 + tid;
  const float* w0p = W_ih + (size_t)j0 * ED;
  const float* w1p = W_ih + (size_t)(j0 + 256) * ED;
  for (int e = 0; e < ED; e++){
    float w0 = w0p[e], w1 = w1p[e];
    #pragma unroll
    for (int b = 0; b < BB; b++){
      float ev = e_s[b * ED + e];
      acc[0][b] = fmaf(ev, w0, acc[0][b]);
      acc[1][b] = fmaf(ev, w1, acc[1][b]);
    }
  }
  #pragma unroll
  for (int r = 0; r < 2; r++){
    int j = j0 + r * 256;
    float bias = b_ih[j] + b_hh[j];
    #pragma unroll
    for (int b = 0; b < BB; b++)
      xg[((size_t)b * UP1 + u) * 2048 + j] = acc[r][b] + bias;
  }
}

// ---------------- K2: persistent LSTM — R3 structure (register-blocked dot) ----------------
// 64 WGs x 256 thr. WG wg owns hidden units [8*wg,+8) -> 32 gate rows.
// Thread (jg=tid>>5, kc=tid&31): acc[4 rows][8 batches] over k-slice kc+32i.
// h via dense ping-pong hb[2][4096]; sync via atomicAdd on cnt[u] + tid0 poll.
__global__ __launch_bounds__(256) void k_lstm_all(
    const float* __restrict__ xg, const float* __restrict__ W_hh,
    float* __restrict__ pred, float* __restrict__ hb, unsigned int* __restrict__ cnt)
{
  __shared__ float h_s[8][520];
  __shared__ float red[32 * 257];
  __shared__ float gates_s[32][9];
  const int tid = threadIdx.x;
  const int wg  = blockIdx.x;
  const int p0  = wg * 8;
  const int jg = tid >> 5, kc = tid & 31;
  const float* wrow[4];
  #pragma unroll
  for (int r = 0; r < 4; r++){
    int jl = jg * 4 + r;                       // 0..31, jl = g*8 + pl
    int grow = (jl >> 3) * PD + p0 + (jl & 7); // W_hh row
    wrow[r] = W_hh + (size_t)grow * PD;
  }
  float c_reg = 0.0f;                          // cell state (tid<64)
  for (int u = 0; u < UP1; u++){
    // x-gate prefetch (independent of h)
    float xi = 0.f, xf = 0.f, xgv = 0.f, xo = 0.f;
    if (tid < 64){
      int pl = tid >> 3, b = tid & 7;
      const float* xr = xg + ((size_t)(b * UP1 + u)) * 2048;
      int p = p0 + pl;
      xi = xr[p]; xf = xr[512 + p]; xgv = xr[1024 + p]; xo = xr[1536 + p];
    }
    if (u > 0){
      if (tid == 0){
        while (__hip_atomic_load(&cnt[u - 1], __ATOMIC_RELAXED, __HIP_MEMORY_SCOPE_AGENT) < LSTM_NWG)
          __builtin_amdgcn_s_sleep(2);
      }
      __syncthreads();
      // coherent h load from dense ping-pong, batched (16 loads in flight)
      const float* hsrc = hb + ((u - 1) & 1) * 4096;
      float tmp[16];
      #pragma unroll
      for (int j = 0; j < 16; j++)
        tmp[j] = __hip_atomic_load(hsrc + tid + 256 * j,
                                   __ATOMIC_RELAXED, __HIP_MEMORY_SCOPE_AGENT);
      #pragma unroll
      for (int j = 0; j < 16; j++){
        int i = tid + 256 * j;
        h_s[i >> 9][i & 511] = tmp[j];
      }
    } else {
      for (int i = tid; i < 8 * PD; i += 256) h_s[i >> 9][i & 511] = 0.0f;
    }
    __syncthreads();
    float acc[4][BB];
    #pragma unroll
    for (int r = 0; r < 4; r++)
      #pragma unroll
      for (int b = 0; b < BB; b++) acc[r][b] = 0.0f;
    for (int i = 0; i < 16; i++){
      int k = kc + 32 * i;
      float hv[BB];
      #pragma unroll
      for (int b = 0; b < BB; b++) hv[b] = h_s[b][k];
      #pragma unroll
      for (int r = 0; r < 4; r++){
        float wv = wrow[r][k];
        #pragma unroll
        for (int b = 0; b < BB; b++) acc[r][b] = fmaf(hv[b], wv, acc[r][b]);
      }
    }
    #pragma unroll
    for (int r = 0; r < 4; r++)
      #pragma unroll
      for (int b = 0; b < BB; b++)
        red[kc * 257 + jg * 32 + r * 8 + b] = acc[r][b];
    __syncthreads();
    {
      int jl = tid >> 3, b = tid & 7;
      float s = 0.0f;
      #pragma unroll
      for (int kk = 0; kk < 32; kk++)
        s += red[kk * 257 + (jl >> 2) * 32 + (jl & 3) * 8 + b];
      gates_s[jl][b] = s;
    }
    __syncthreads();
    if (tid < 64){
      int pl = tid >> 3, b2 = tid & 7;
      int p = p0 + pl;
      float gi = gates_s[0  + pl][b2] + xi;
      float gf = gates_s[8  + pl][b2] + xf;
      float gg = gates_s[16 + pl][b2] + xgv;
      float go = gates_s[24 + pl][b2] + xo;
      float iv = sigm(gi), fv = sigm(gf), ov = sigm(go);
      c_reg = fv * c_reg + iv * tanh_fast(gg);
      float hval = ov * tanh_fast(c_reg);
      __hip_atomic_store(hb + (u & 1) * 4096 + b2 * 512 + p, hval,
                         __ATOMIC_RELAXED, __HIP_MEMORY_SCOPE_AGENT);
      pred[((size_t)(b2 * UP1 + u)) * PD + p] = hval;   // for f_pred gemm
    }
    if (u < UP1 - 1 && tid == 0){
      asm volatile("s_waitcnt vmcnt(0)" ::: "memory");  // wave-0 h stores retired
      __hip_atomic_fetch_add(&cnt[u], 1u, __ATOMIC_RELAXED, __HIP_MEMORY_SCOPE_AGENT);
    }
  }
}

// ---------------- K3: fp32 GEMM (A @ W^T + bias) -> bf16 out ----------------
__global__ __launch_bounds__(256) void k_gemm_bias_bf16(
    const float* __restrict__ A, const float* __restrict__ W,
    const float* __restrict__ bias, unsigned short* __restrict__ out, int M)
{
  __shared__ float a_s[16][68];
  __shared__ float b_s[16][68];
  const int m0 = blockIdx.x * 64, n0 = blockIdx.y * 64;
  const int tid = threadIdx.x;
  const int tx = tid & 15, ty = tid >> 4;
  float acc[4][4];
  #pragma unroll
  for (int i2 = 0; i2 < 4; i2++)
    #pragma unroll
    for (int j2 = 0; j2 < 4; j2++) acc[i2][j2] = 0.0f;
  for (int k0 = 0; k0 < 512; k0 += 16){
    int mm = tid >> 2, k4 = (tid & 3) * 4;
    int row = m0 + mm; if (row >= M) row = M - 1;
    float4 av = *(const float4*)(A + (size_t)row * 512 + k0 + k4);
    a_s[k4 + 0][mm] = av.x; a_s[k4 + 1][mm] = av.y;
    a_s[k4 + 2][mm] = av.z; a_s[k4 + 3][mm] = av.w;
    float4 bv = *(const float4*)(W + (size_t)(n0 + mm) * 512 + k0 + k4);
    b_s[k4 + 0][mm] = bv.x; b_s[k4 + 1][mm] = bv.y;
    b_s[k4 + 2][mm] = bv.z; b_s[k4 + 3][mm] = bv.w;
    __syncthreads();
    #pragma unroll
    for (int k = 0; k < 16; k++){
      float4 a4 = *(const float4*)&a_s[k][ty * 4];
      float4 b4 = *(const float4*)&b_s[k][tx * 4];
      float aa[4] = {a4.x, a4.y, a4.z, a4.w};
      float bb[4] = {b4.x, b4.y, b4.z, b4.w};
      #pragma unroll
      for (int i2 = 0; i2 < 4; i2++)
        #pragma unroll
        for (int j2 = 0; j2 < 4; j2++)
          acc[i2][j2] = fmaf(aa[i2], bb[j2], acc[i2][j2]);
    }
    __syncthreads();
  }
  #pragma unroll
  for (int i2 = 0; i2 < 4; i2++){
    int m = m0 + ty * 4 + i2;
    if (m < M){
      #pragma unroll
      for (int j2 = 0; j2 < 4; j2++){
        int n = n0 + tx * 4 + j2;
        out[(size_t)m * 512 + n] = f2bf(acc[i2][j2] + bias[n]);
      }
    }
  }
}

// ---------------- K4: joint as m97-style GEMM ----------------
// M = 161600 flat rows (b,t,u), N = 1024 (col 1024 in k_blank), K = 512.
// grid (1263, 8): 128x128 tile, BK=64, dbuf A/B in 64KB LDS -> 2 blocks/CU.
// 4 waves, each 64x64 quadrant (acc 4x4). tanh fused into A staging (reg-staged,
// XOR-swizzled LDS writes); loads issued before MFMAs (T14 split).
__global__ __launch_bounds__(256, 2) void k_joint6(
    const unsigned short* __restrict__ fe, const unsigned short* __restrict__ fp,
    const unsigned short* __restrict__ wj, const float* __restrict__ bj,
    float* __restrict__ out)
{
  __shared__ unsigned short A_s[2][128 * 64];   // 2 x 16KB
  __shared__ unsigned short B_s[2][128 * 64];   // 2 x 16KB
  const int m0 = blockIdx.x * 128;
  const int n0 = blockIdx.y * 128;
  const int tid = threadIdx.x;
  const int w = tid >> 6, l = tid & 63;
  const int l15 = l & 15, lg = l >> 4;
  const int wr = w >> 1, wc = w & 1;

  // staging mapping: thread -> (row sr, k-half sh)
  const int sr = tid >> 1;
  const int sh = (tid & 1) * 32;
  int mclamp = m0 + sr; if (mclamp >= MTOT) mclamp = MTOT - 1;
  const int q  = mclamp / 101;          // b*200 + t
  const int su = mclamp - q * 101;      // u
  const int sb = q / 200;               // b
  const unsigned short* fe_row = fe + (size_t)q * 512 + sh;
  const unsigned short* fp_row = fp + (size_t)(sb * 101 + su) * 512 + sh;
  const unsigned short* wj_row = wj + (size_t)(n0 + sr) * 512 + sh;

  ushort8 rfe[4], rfp[4], rwj[4];
  auto load_regs = [&](int kc0){
    #pragma unroll
    for (int j = 0; j < 4; j++){
      rfe[j] = *(const ushort8*)(fe_row + kc0 + j * 8);
      rfp[j] = *(const ushort8*)(fp_row + kc0 + j * 8);
      rwj[j] = *(const ushort8*)(wj_row + kc0 + j * 8);
    }
  };
  auto write_lds = [&](int buf){
    #pragma unroll
    for (int j = 0; j < 4; j++){
      ushort8 a;
      #pragma unroll
      for (int e = 0; e < 8; e++)
        a[e] = f2bf(tanh_fast(bf2f(rfe[j][e]) + bf2f(rfp[j][e])));
      int byo = sr * 128 + (((sh + j * 8) * 2) ^ ((sr & 7) << 4));
      *(ushort8*)((char*)A_s[buf] + byo) = a;
      *(ushort8*)((char*)B_s[buf] + byo) = rwj[j];
    }
  };

  load_regs(0);
  write_lds(0);
  __syncthreads();

  f32x4 acc[4][4];
  #pragma unroll
  for (int fr = 0; fr < 4; fr++)
    #pragma unroll
    for (int fc = 0; fc < 4; fc++)
      acc[fr][fc] = (f32x4){0.f, 0.f, 0.f, 0.f};

  for (int kc = 0; kc < 8; kc++){
    const int buf = kc & 1;
    if (kc < 7) load_regs((kc + 1) * 64);   // HBM/L2 latency hides under MFMAs
    #pragma unroll
    for (int ks = 0; ks < 2; ks++){
      bf16x8 afr[4], bfr[4];
      #pragma unroll
      for (int f = 0; f < 4; f++){
        int ra = wr * 64 + f * 16 + l15;
        int bya = ra * 128 + ((ks * 64 + lg * 16) ^ ((ra & 7) << 4));
        afr[f] = __builtin_bit_cast(bf16x8, *(const ushort8*)((const char*)A_s[buf] + bya));
        int rb = wc * 64 + f * 16 + l15;
        int byb = rb * 128 + ((ks * 64 + lg * 16) ^ ((rb & 7) << 4));
        bfr[f] = __builtin_bit_cast(bf16x8, *(const ushort8*)((const char*)B_s[buf] + byb));
      }
      #pragma unroll
      for (int fr = 0; fr < 4; fr++)
        #pragma unroll
        for (int fc = 0; fc < 4; fc++)
          acc[fr][fc] = __builtin_amdgcn_mfma_f32_16x16x32_bf16(bfr[fc], afr[fr], acc[fr][fc], 0, 0, 0);
    }
    if (kc < 7) write_lds(buf ^ 1);         // tanh + swizzled LDS write to other buffer
    __syncthreads();
  }

  // epilogue: C reg-dim = n (col), lane l15 = m (row)
  #pragma unroll
  for (int fr = 0; fr < 4; fr++){
    int m = m0 + wr * 64 + fr * 16 + l15;
    if (m < MTOT){
      float* orow = out + (size_t)m * VP1;
      #pragma unroll
      for (int fc = 0; fc < 4; fc++){
        int col = n0 + wc * 64 + fc * 16 + lg * 4;
        float4 bv = *(const float4*)(bj + col);
        f32x4 v = acc[fr][fc];
        float4 st = {v[0] + bv.x, v[1] + bv.y, v[2] + bv.z, v[3] + bv.w};
        *(float4*)(orow + col) = st;
      }
    }
  }
}

// ---------------- K5: blank-logit column (col 1024) ----------------
__global__ __launch_bounds__(256) void k_blank(
    const unsigned short* __restrict__ fe, const unsigned short* __restrict__ fp,
    const unsigned short* __restrict__ wj, const float* __restrict__ bj,
    float* __restrict__ out)
{
  __shared__ float w_s[512];
  const int tid = threadIdx.x;
  const unsigned short* w1 = wj + (size_t)1024 * 512;
  w_s[tid]       = bf2f(w1[tid]);
  w_s[tid + 256] = bf2f(w1[tid + 256]);
  __syncthreads();
  int m = blockIdx.x * 256 + tid;
  if (m >= MTOT) return;
  const int q  = m / 101;
  const int u  = m - q * 101;
  const int b  = q / 200;
  const unsigned short* fe_row = fe + (size_t)q * 512;
  const unsigned short* fp_row = fp + (size_t)(b * 101 + u) * 512;
  float s = 0.0f;
  #pragma unroll 4
  for (int k = 0; k < 512; k += 8){
    ushort8 f8 = *(const ushort8*)(fe_row + k);
    ushort8 p8 = *(const ushort8*)(fp_row + k);
    #pragma unroll
    for (int e = 0; e < 8; e++)
      s += tanh_fast(bf2f(f8[e]) + bf2f(p8[e])) * w_s[k + e];
  }
  out[(size_t)m * VP1 + 1024] = s + bj[1024];
}

extern "C" void kernel_launch(void* const* d_in, const int* in_sizes, int n_in,
                              void* d_out, int out_size, void* d_ws, size_t ws_size,
                              hipStream_t stream) {
  const float* enc_out = (const float*)d_in[0];
  const int*   targets = (const int*)d_in[1];
  const float* emb     = (const float*)d_in[3];
  const float* W_ih    = (const float*)d_in[4];
  const float* W_hh    = (const float*)d_in[5];
  const float* b_ih    = (const float*)d_in[6];
  const float* b_hh    = (const float*)d_in[7];
  const float* W_enc   = (const float*)d_in[8];
  const float* b_enc   = (const float*)d_in[9];
  const float* W_pred  = (const float*)d_in[10];
  const float* b_pred  = (const float*)d_in[11];
  const float* W_joint = (const float*)d_in[12];
  const float* b_joint = (const float*)d_in[13];
  float* out = (float*)d_out;

  char* ws = (char*)d_ws;
  float* xg            = (float*)(ws + 0);                  // 6,619,136 B
  float* pred          = (float*)(ws + 6619136);            // 1,654,784 B
  unsigned short* feb  = (unsigned short*)(ws + 8273920);   // 1,638,400 B
  unsigned short* fpb  = (unsigned short*)(ws + 9912320);   //   827,392 B
  unsigned short* wjb  = (unsigned short*)(ws + 10739712);  // 1,049,600 B
  float* hb            = (float*)(ws + 11789312);           //    32,768 B
  unsigned int* cnt    = (unsigned int*)(ws + 11822080);    //       404 B

  (void)hipMemsetAsync(cnt, 0, UP1 * sizeof(unsigned int), stream);
  hipLaunchKernelGGL(k_cvt_bf16, dim3((VP1 * 512 + 255) / 256), dim3(256), 0, stream,
                     W_joint, wjb, VP1 * 512);
  hipLaunchKernelGGL(k_xgate, dim3(404), dim3(256), 0, stream,
                     emb, targets, W_ih, b_ih, b_hh, xg);
  hipLaunchKernelGGL(k_gemm_bias_bf16, dim3(25, 8), dim3(256), 0, stream,
                     enc_out, W_enc, b_enc, feb, 1600);
  hipLaunchKernelGGL(k_lstm_all, dim3(LSTM_NWG), dim3(256), 0, stream,
                     xg, W_hh, pred, hb, cnt);
  hipLaunchKernelGGL(k_gemm_bias_bf16, dim3(13, 8), dim3(256), 0, stream,
                     pred, W_pred, b_pred, fpb, 808);
  hipLaunchKernelGGL(k_joint6, dim3(1263, 8), dim3(256), 0, stream,
                     feb, fpb, wjb, b_joint, out);
  hipLaunchKernelGGL(k_blank, dim3((MTOT + 255) / 256), dim3(256), 0, stream,
                     feb, fpb, wjb, b_joint, out);
}

// Round 9
// 993.560 us; speedup vs baseline: 1.6782x; 1.1290x over previous
//
#include <hip/hip_runtime.h>
#include <stdint.h>
#include <stddef.h>

#define BB 8
#define TENC 200
#define UU 100
#define UP1 101
#define VP1 1025
#define ED 128
#define PD 512
#define LSTM_NWG 64
#define MTOT 161600   // 8*200*101 flattened output rows
#define MB_  20200    // rows per batch (200*101)

typedef __attribute__((ext_vector_type(8))) unsigned short ushort8;
typedef __attribute__((ext_vector_type(8))) __bf16 bf16x8;
typedef __attribute__((ext_vector_type(4))) float f32x4;

__device__ __forceinline__ float bf2f(unsigned short u){
  unsigned int x = ((unsigned int)u) << 16;
  return __builtin_bit_cast(float, x);
}
__device__ __forceinline__ unsigned short f2bf(float f){
  unsigned int x = __builtin_bit_cast(unsigned int, f);
  unsigned int r = (x + 0x7fffu + ((x >> 16) & 1u)) >> 16;
  return (unsigned short)r;
}
__device__ __forceinline__ float tanh_fast(float x){
  float e = __expf(2.0f * x);
  return 1.0f - 2.0f / (e + 1.0f);
}
__device__ __forceinline__ float sigm(float x){
  return 1.0f / (1.0f + __expf(-x));
}
__device__ __forceinline__ void gload_lds16(const unsigned short* gsrc, unsigned short* ldst){
  __builtin_amdgcn_global_load_lds((const __attribute__((address_space(1))) void*)gsrc,
                                   (__attribute__((address_space(3))) void*)ldst, 16, 0, 0);
}

// ---------------- fp32 -> bf16 convert (W_joint) ----------------
__global__ __launch_bounds__(256) void k_cvt_bf16(const float* __restrict__ src,
                                                  unsigned short* __restrict__ dst, int n){
  int i = blockIdx.x * 256 + threadIdx.x;
  if (i < n) dst[i] = f2bf(src[i]);
}

// ---------------- K1: embedding + x-part of LSTM gates ----------------
__global__ __launch_bounds__(256) void k_xgate(
    const float* __restrict__ emb, const int* __restrict__ targets,
    const float* __restrict__ W_ih, const float* __restrict__ b_ih,
    const float* __restrict__ b_hh, float* __restrict__ xg)
{
  __shared__ float e_s[BB * ED];
  const int u  = blockIdx.x >> 2;
  const int jq = blockIdx.x & 3;
  const int tid = threadIdx.x;
  for (int idx = tid; idx < BB * ED; idx += 256){
    int b = idx >> 7, e = idx & 127;
    int tok = (u == 0) ? 1024 : targets[b * UU + (u - 1)];
    e_s[idx] = emb[(size_t)tok * ED + e];
  }
  __syncthreads();
  float acc[2][BB];
  #pragma unroll
  for (int r = 0; r < 2; r++)
    #pragma unroll
    for (int b = 0; b < BB; b++) acc[r][b] = 0.0f;
  const int j0 = jq * 512 + tid;
  const float* w0p = W_ih + (size_t)j0 * ED;
  const float* w1p = W_ih + (size_t)(j0 + 256) * ED;
  for (int e = 0; e < ED; e++){
    float w0 = w0p[e], w1 = w1p[e];
    #pragma unroll
    for (int b = 0; b < BB; b++){
      float ev = e_s[b * ED + e];
      acc[0][b] = fmaf(ev, w0, acc[0][b]);
      acc[1][b] = fmaf(ev, w1, acc[1][b]);
    }
  }
  #pragma unroll
  for (int r = 0; r < 2; r++){
    int j = j0 + r * 256;
    float bias = b_ih[j] + b_hh[j];
    #pragma unroll
    for (int b = 0; b < BB; b++)
      xg[((size_t)b * UP1 + u) * 2048 + j] = acc[r][b] + bias;
  }
}

// ---------------- K2: persistent LSTM — R3 structure (register-blocked dot) ----------------
__global__ __launch_bounds__(256) void k_lstm_all(
    const float* __restrict__ xg, const float* __restrict__ W_hh,
    float* __restrict__ pred, float* __restrict__ hb, unsigned int* __restrict__ cnt)
{
  __shared__ float h_s[8][520];
  __shared__ float red[32 * 257];
  __shared__ float gates_s[32][9];
  const int tid = threadIdx.x;
  const int wg  = blockIdx.x;
  const int p0  = wg * 8;
  const int jg = tid >> 5, kc = tid & 31;
  const float* wrow[4];
  #pragma unroll
  for (int r = 0; r < 4; r++){
    int jl = jg * 4 + r;
    int grow = (jl >> 3) * PD + p0 + (jl & 7);
    wrow[r] = W_hh + (size_t)grow * PD;
  }
  float c_reg = 0.0f;
  for (int u = 0; u < UP1; u++){
    float xi = 0.f, xf = 0.f, xgv = 0.f, xo = 0.f;
    if (tid < 64){
      int pl = tid >> 3, b = tid & 7;
      const float* xr = xg + ((size_t)(b * UP1 + u)) * 2048;
      int p = p0 + pl;
      xi = xr[p]; xf = xr[512 + p]; xgv = xr[1024 + p]; xo = xr[1536 + p];
    }
    if (u > 0){
      if (tid == 0){
        while (__hip_atomic_load(&cnt[u - 1], __ATOMIC_RELAXED, __HIP_MEMORY_SCOPE_AGENT) < LSTM_NWG)
          __builtin_amdgcn_s_sleep(2);
      }
      __syncthreads();
      const float* hsrc = hb + ((u - 1) & 1) * 4096;
      float tmp[16];
      #pragma unroll
      for (int j = 0; j < 16; j++)
        tmp[j] = __hip_atomic_load(hsrc + tid + 256 * j,
                                   __ATOMIC_RELAXED, __HIP_MEMORY_SCOPE_AGENT);
      #pragma unroll
      for (int j = 0; j < 16; j++){
        int i = tid + 256 * j;
        h_s[i >> 9][i & 511] = tmp[j];
      }
    } else {
      for (int i = tid; i < 8 * PD; i += 256) h_s[i >> 9][i & 511] = 0.0f;
    }
    __syncthreads();
    float acc[4][BB];
    #pragma unroll
    for (int r = 0; r < 4; r++)
      #pragma unroll
      for (int b = 0; b < BB; b++) acc[r][b] = 0.0f;
    for (int i = 0; i < 16; i++){
      int k = kc + 32 * i;
      float hv[BB];
      #pragma unroll
      for (int b = 0; b < BB; b++) hv[b] = h_s[b][k];
      #pragma unroll
      for (int r = 0; r < 4; r++){
        float wv = wrow[r][k];
        #pragma unroll
        for (int b = 0; b < BB; b++) acc[r][b] = fmaf(hv[b], wv, acc[r][b]);
      }
    }
    #pragma unroll
    for (int r = 0; r < 4; r++)
      #pragma unroll
      for (int b = 0; b < BB; b++)
        red[kc * 257 + jg * 32 + r * 8 + b] = acc[r][b];
    __syncthreads();
    {
      int jl = tid >> 3, b = tid & 7;
      float s = 0.0f;
      #pragma unroll
      for (int kk = 0; kk < 32; kk++)
        s += red[kk * 257 + (jl >> 2) * 32 + (jl & 3) * 8 + b];
      gates_s[jl][b] = s;
    }
    __syncthreads();
    if (tid < 64){
      int pl = tid >> 3, b2 = tid & 7;
      int p = p0 + pl;
      float gi = gates_s[0  + pl][b2] + xi;
      float gf = gates_s[8  + pl][b2] + xf;
      float gg = gates_s[16 + pl][b2] + xgv;
      float go = gates_s[24 + pl][b2] + xo;
      float iv = sigm(gi), fv = sigm(gf), ov = sigm(go);
      c_reg = fv * c_reg + iv * tanh_fast(gg);
      float hval = ov * tanh_fast(c_reg);
      __hip_atomic_store(hb + (u & 1) * 4096 + b2 * 512 + p, hval,
                         __ATOMIC_RELAXED, __HIP_MEMORY_SCOPE_AGENT);
      pred[((size_t)(b2 * UP1 + u)) * PD + p] = hval;
    }
    if (u < UP1 - 1 && tid == 0){
      asm volatile("s_waitcnt vmcnt(0)" ::: "memory");
      __hip_atomic_fetch_add(&cnt[u], 1u, __ATOMIC_RELAXED, __HIP_MEMORY_SCOPE_AGENT);
    }
  }
}

// ---------------- K3: fp32 GEMM (A @ W^T + bias) -> bf16 out ----------------
__global__ __launch_bounds__(256) void k_gemm_bias_bf16(
    const float* __restrict__ A, const float* __restrict__ W,
    const float* __restrict__ bias, unsigned short* __restrict__ out, int M)
{
  __shared__ float a_s[16][68];
  __shared__ float b_s[16][68];
  const int m0 = blockIdx.x * 64, n0 = blockIdx.y * 64;
  const int tid = threadIdx.x;
  const int tx = tid & 15, ty = tid >> 4;
  float acc[4][4];
  #pragma unroll
  for (int i2 = 0; i2 < 4; i2++)
    #pragma unroll
    for (int j2 = 0; j2 < 4; j2++) acc[i2][j2] = 0.0f;
  for (int k0 = 0; k0 < 512; k0 += 16){
    int mm = tid >> 2, k4 = (tid & 3) * 4;
    int row = m0 + mm; if (row >= M) row = M - 1;
    float4 av = *(const float4*)(A + (size_t)row * 512 + k0 + k4);
    a_s[k4 + 0][mm] = av.x; a_s[k4 + 1][mm] = av.y;
    a_s[k4 + 2][mm] = av.z; a_s[k4 + 3][mm] = av.w;
    float4 bv = *(const float4*)(W + (size_t)(n0 + mm) * 512 + k0 + k4);
    b_s[k4 + 0][mm] = bv.x; b_s[k4 + 1][mm] = bv.y;
    b_s[k4 + 2][mm] = bv.z; b_s[k4 + 3][mm] = bv.w;
    __syncthreads();
    #pragma unroll
    for (int k = 0; k < 16; k++){
      float4 a4 = *(const float4*)&a_s[k][ty * 4];
      float4 b4 = *(const float4*)&b_s[k][tx * 4];
      float aa[4] = {a4.x, a4.y, a4.z, a4.w};
      float bb[4] = {b4.x, b4.y, b4.z, b4.w};
      #pragma unroll
      for (int i2 = 0; i2 < 4; i2++)
        #pragma unroll
        for (int j2 = 0; j2 < 4; j2++)
          acc[i2][j2] = fmaf(aa[i2], bb[j2], acc[i2][j2]);
    }
    __syncthreads();
  }
  #pragma unroll
  for (int i2 = 0; i2 < 4; i2++){
    int m = m0 + ty * 4 + i2;
    if (m < M){
      #pragma unroll
      for (int j2 = 0; j2 < 4; j2++){
        int n = n0 + tx * 4 + j2;
        out[(size_t)m * 512 + n] = f2bf(acc[i2][j2] + bias[n]);
      }
    }
  }
}

// ---------------- K4a: precompute A = tanh(fe+fp) bf16, + fused blank column ----------------
// block: 256 thr = 4 rows x 64 lanes (8 elems each). Also computes
// out[m*1025+1024] = tanh-row . W_joint[1024] + bj[1024] via 64-lane shfl reduce.
__global__ __launch_bounds__(256) void k_tanhA(
    const unsigned short* __restrict__ fe, const unsigned short* __restrict__ fp,
    const unsigned short* __restrict__ wj, const float* __restrict__ bj,
    unsigned short* __restrict__ Aout, float* __restrict__ out,
    int m_base, int M_cnt)
{
  const int tid = threadIdx.x;
  const int mlocal = blockIdx.x * 4 + (tid >> 6);
  if (mlocal >= M_cnt) return;
  const int l = tid & 63;
  const int m = m_base + mlocal;
  const int q = m / 101;            // b*200 + t
  const int u = m - q * 101;
  const int b = q / 200;
  ushort8 f8 = *(const ushort8*)(fe + (size_t)q * 512 + l * 8);
  ushort8 p8 = *(const ushort8*)(fp + (size_t)(b * 101 + u) * 512 + l * 8);
  ushort8 w8 = *(const ushort8*)(wj + (size_t)1024 * 512 + l * 8);
  ushort8 a;
  float s = 0.0f;
  #pragma unroll
  for (int e = 0; e < 8; e++){
    float v = tanh_fast(bf2f(f8[e]) + bf2f(p8[e]));
    a[e] = f2bf(v);
    s += v * bf2f(w8[e]);
  }
  *(ushort8*)(Aout + (size_t)mlocal * 512 + l * 8) = a;
  #pragma unroll
  for (int off = 1; off < 64; off <<= 1) s += __shfl_xor(s, off);
  if (l == 0) out[(size_t)m * VP1 + 1024] = s + bj[1024];
}

// ---------------- K4b: joint GEMM (m97 structure, global_load_lds staging) ----------------
// C[m][n] = A[m][:].Wj[n][:] + bj[n], 128x128 tiles, BK=64, dbuf, 2 blocks/CU.
// Staging: global_load_lds w16, linear LDS dest, PRE-SWIZZLED global source;
// reads use joint6's verified XOR-swizzled pattern (0 bank conflicts).
__global__ __launch_bounds__(256, 2) void k_joint7(
    const unsigned short* __restrict__ A, const unsigned short* __restrict__ wj,
    const float* __restrict__ bj, float* __restrict__ out, int m_base, int M_cnt)
{
  __shared__ unsigned short A_s[2][128 * 64];   // 2 x 16KB
  __shared__ unsigned short B_s[2][128 * 64];   // 2 x 16KB
  const int n0 = blockIdx.x * 128;              // n-tile fastest: 8 sharers of A-panel adjacent
  const int m0 = blockIdx.y * 128;
  const int tid = threadIdx.x;
  const int w = tid >> 6, l = tid & 63;
  const int l15 = l & 15, lg = l >> 4;
  const int wr = w >> 1, wc = w & 1;
  const int srow = l >> 3;                      // row within 8-row chunk
  const int scc  = l & 7;                       // 16B sub-chunk

  // one chunk c covers tile rows [c*8, c*8+8), 1KB linear LDS; source pre-swizzled
  auto stage = [&](int buf, int kc){
    #pragma unroll
    for (int i = 0; i < 4; i++){
      int c = w * 4 + i;                        // wave-uniform chunk id 0..15
      int r = c * 8 + srow;                     // tile row 0..127
      int koff = kc * 64 + ((scc ^ (r & 7)) * 8);
      int ra = m0 + r; if (ra >= M_cnt) ra = M_cnt - 1;
      gload_lds16(A + (size_t)ra * 512 + koff,
                  (unsigned short*)A_s[buf] + (size_t)c * 512);
      gload_lds16(wj + (size_t)(n0 + r) * 512 + koff,
                  (unsigned short*)B_s[buf] + (size_t)c * 512);
    }
  };

  stage(0, 0);
  __syncthreads();   // drains vmcnt before barrier

  f32x4 acc[4][4];
  #pragma unroll
  for (int fr = 0; fr < 4; fr++)
    #pragma unroll
    for (int fc = 0; fc < 4; fc++)
      acc[fr][fc] = (f32x4){0.f, 0.f, 0.f, 0.f};

  for (int kc = 0; kc < 8; kc++){
    const int buf = kc & 1;
    if (kc < 7) stage(buf ^ 1, kc + 1);         // DMA overlaps MFMAs below
    #pragma unroll
    for (int ks = 0; ks < 2; ks++){
      bf16x8 afr[4], bfr[4];
      #pragma unroll
      for (int f = 0; f < 4; f++){
        int ra = wr * 64 + f * 16 + l15;
        int bya = ra * 128 + ((ks * 64 + lg * 16) ^ ((ra & 7) << 4));
        afr[f] = __builtin_bit_cast(bf16x8, *(const ushort8*)((const char*)A_s[buf] + bya));
        int rb = wc * 64 + f * 16 + l15;
        int byb = rb * 128 + ((ks * 64 + lg * 16) ^ ((rb & 7) << 4));
        bfr[f] = __builtin_bit_cast(bf16x8, *(const ushort8*)((const char*)B_s[buf] + byb));
      }
      #pragma unroll
      for (int fr = 0; fr < 4; fr++)
        #pragma unroll
        for (int fc = 0; fc < 4; fc++)
          acc[fr][fc] = __builtin_amdgcn_mfma_f32_16x16x32_bf16(bfr[fc], afr[fr], acc[fr][fc], 0, 0, 0);
    }
    __syncthreads();                            // prev MFMA done + this kc's DMA drained
  }

  // epilogue: C reg-dim = n (col), lane l15 = m (row)
  #pragma unroll
  for (int fr = 0; fr < 4; fr++){
    int mloc = m0 + wr * 64 + fr * 16 + l15;
    if (mloc < M_cnt){
      float* orow = out + (size_t)(m_base + mloc) * VP1;
      #pragma unroll
      for (int fc = 0; fc < 4; fc++){
        int col = n0 + wc * 64 + fc * 16 + lg * 4;
        float4 bv = *(const float4*)(bj + col);
        f32x4 v = acc[fr][fc];
        float4 st = {v[0] + bv.x, v[1] + bv.y, v[2] + bv.z, v[3] + bv.w};
        *(float4*)(orow + col) = st;
      }
    }
  }
}

extern "C" void kernel_launch(void* const* d_in, const int* in_sizes, int n_in,
                              void* d_out, int out_size, void* d_ws, size_t ws_size,
                              hipStream_t stream) {
  const float* enc_out = (const float*)d_in[0];
  const int*   targets = (const int*)d_in[1];
  const float* emb     = (const float*)d_in[3];
  const float* W_ih    = (const float*)d_in[4];
  const float* W_hh    = (const float*)d_in[5];
  const float* b_ih    = (const float*)d_in[6];
  const float* b_hh    = (const float*)d_in[7];
  const float* W_enc   = (const float*)d_in[8];
  const float* b_enc   = (const float*)d_in[9];
  const float* W_pred  = (const float*)d_in[10];
  const float* b_pred  = (const float*)d_in[11];
  const float* W_joint = (const float*)d_in[12];
  const float* b_joint = (const float*)d_in[13];
  float* out = (float*)d_out;

  char* ws = (char*)d_ws;
  float* xg            = (float*)(ws + 0);                  // 6,619,136 B
  float* pred          = (float*)(ws + 6619136);            // 1,654,784 B
  unsigned short* feb  = (unsigned short*)(ws + 8273920);   // 1,638,400 B
  unsigned short* fpb  = (unsigned short*)(ws + 9912320);   //   827,392 B
  unsigned short* wjb  = (unsigned short*)(ws + 10739712);  // 1,049,600 B
  float* hb            = (float*)(ws + 11789312);           //    32,768 B
  unsigned int* cnt    = (unsigned int*)(ws + 11822080);    //       404 B
  unsigned short* Abuf = (unsigned short*)(ws + 11825152);  // A workspace
  const size_t FULL_NEED  = 11825152 + (size_t)MTOT * 512 * 2;  // ~177.3 MB
  const size_t BATCH_NEED = 11825152 + (size_t)MB_  * 512 * 2;  // ~32.5 MB

  (void)hipMemsetAsync(cnt, 0, UP1 * sizeof(unsigned int), stream);
  hipLaunchKernelGGL(k_cvt_bf16, dim3((VP1 * 512 + 255) / 256), dim3(256), 0, stream,
                     W_joint, wjb, VP1 * 512);
  hipLaunchKernelGGL(k_xgate, dim3(404), dim3(256), 0, stream,
                     emb, targets, W_ih, b_ih, b_hh, xg);
  hipLaunchKernelGGL(k_gemm_bias_bf16, dim3(25, 8), dim3(256), 0, stream,
                     enc_out, W_enc, b_enc, feb, 1600);
  hipLaunchKernelGGL(k_lstm_all, dim3(LSTM_NWG), dim3(256), 0, stream,
                     xg, W_hh, pred, hb, cnt);
  hipLaunchKernelGGL(k_gemm_bias_bf16, dim3(13, 8), dim3(256), 0, stream,
                     pred, W_pred, b_pred, fpb, 808);

  if (ws_size >= FULL_NEED){
    hipLaunchKernelGGL(k_tanhA, dim3(MTOT / 4), dim3(256), 0, stream,
                       feb, fpb, wjb, b_joint, Abuf, out, 0, MTOT);
    hipLaunchKernelGGL(k_joint7, dim3(8, 1263), dim3(256), 0, stream,
                       Abuf, wjb, b_joint, out, 0, MTOT);
  } else if (ws_size >= BATCH_NEED){
    for (int b = 0; b < 8; b++){
      hipLaunchKernelGGL(k_tanhA, dim3(MB_ / 4), dim3(256), 0, stream,
                         feb, fpb, wjb, b_joint, Abuf, out, b * MB_, MB_);
      hipLaunchKernelGGL(k_joint7, dim3(8, 158), dim3(256), 0, stream,
                         Abuf, wjb, b_joint, out, b * MB_, MB_);
    }
  } else {
    // minimal-ws fallback: quarter-batch A chunks (5050 rows = 5.2 MB)
    for (int c = 0; c < 32; c++){
      hipLaunchKernelGGL(k_tanhA, dim3(5050 / 2, 1), dim3(256), 0, stream,
                         feb, fpb, wjb, b_joint, Abuf, out, c * 5050, 5050);
      hipLaunchKernelGGL(k_joint7, dim3(8, 40), dim3(256), 0, stream,
                         Abuf, wjb, b_joint, out, c * 5050, 5050);
    }
  }
}